// Round 17
// baseline (503.214 us; speedup 1.0000x reference)
//
#include <hip/hip_runtime.h>
#include <hip/hip_fp16.h>
#include <math.h>

#define BB 32
#define LL 40
#define DD 128
#define NSB 64                        // 2 seq * 32 batch
#define NU  (NSB * LL)                // 2560
#define PLANE (DD * DD)               // 16384
#define SLAB ((size_t)NSB * PLANE)    // u16 elements per t-slab (2 MB)

typedef unsigned short u16;
typedef unsigned int u32;

// ---- fp16 helpers (h state is fp16: h in (-1,1) -> fp16 beats bf16 there) ----
__device__ __forceinline__ u16 f2h(float f) {
    __half h = __float2half(f);
    union { __half h; u16 u; } v; v.h = h; return v.u;
}
__device__ __forceinline__ float h2f(u16 b) {
    union { u16 u; __half h; } v; v.u = b; return __half2float(v.h);
}
__device__ __forceinline__ u32 h2bits(__half2 h) {
    union { __half2 h; u32 u; } v; v.h = h; return v.u;
}
__device__ __forceinline__ __half2 bits2h(u32 b) {
    union { u32 u; __half2 h; } v; v.u = b; return v.h;
}

// Fast f32 math: v_rcp_f32 instead of IEEE div (outputs rounded to 16-bit anyway).
__device__ __forceinline__ float rcpf(float x) { return __builtin_amdgcn_rcpf(x); }
__device__ __forceinline__ float sigm(float x)  { return rcpf(1.f + __expf(-x)); }
__device__ __forceinline__ float tanhs(float x) { return fmaf(2.f, rcpf(1.f + __expf(-2.f * x)), -1.f); }

// ---------------- prep: xe rows + inverse squared norms ----------------
__global__ void prep_kernel(const int* __restrict__ q, const int* __restrict__ a,
                            const float* __restrict__ embed,
                            float* __restrict__ xe_all, float* __restrict__ inv_all) {
    int u = blockIdx.x * 4 + (threadIdx.x >> 6);
    int lane = threadIdx.x & 63;
    if (u >= NU) return;
    int sb = u / LL, t = u % LL;
    int s = sb >> 5, b = sb & 31;
    const int* idx = s ? a : q;
    int e = idx[b * LL + t];
    const float* row = embed + (size_t)e * DD;
    float v0 = row[lane], v1 = row[lane + 64];
    xe_all[(size_t)u * DD + lane] = v0;
    xe_all[(size_t)u * DD + lane + 64] = v1;
    float d = v0 * v0 + v1 * v1;
    #pragma unroll
    for (int o = 32; o; o >>= 1) d += __shfl_down(d, o);
    if (lane == 0) inv_all[u] = 1.f / (d + 1e-4f);
}

// ---------------- layer1 rows 0..62: separable density gates + in-block scan ----------------
// 1-D swizzled grid (63*NSB) x 512. Block: one output row i of one sb, all 40 t.
// NOTE: conv weights live in LDS (wls) because the U-computation indexes them at
// RUNTIME — a per-thread w[48] array would spill to scratch (396 MB of traffic).
__global__ __launch_bounds__(512)
void sep0_kernel(const float* __restrict__ xe_all, const float* __restrict__ inv_all,
                 const float* __restrict__ conv_w, const float* __restrict__ conv_b,
                 u16* __restrict__ h1) {
    const int nchunk = (63 * NSB) / 8;
    const int logical = ((int)blockIdx.x % 8) * nchunk + (int)blockIdx.x / 8;
    const int i  = logical % 63;
    const int sb = logical / 63;
    const int tid = threadIdx.x;
    const int cp = tid & 63;
    const int t0 = tid >> 6;          // 0..7, wave-uniform
    const int c0 = 2 * cp;

    __shared__ float xe_s[LL][DD];    // 20.5 KB
    __shared__ float U[LL][12];
    __shared__ u32 gfo_l[LL][DD];     // bf16-packed (fg|og), internal to this kernel
    __shared__ u32 gic_l[LL][DD / 2];
    __shared__ float wls[48];

    if (tid < 48) wls[tid] = conv_w[tid];
    float b4[4];
    #pragma unroll
    for (int k = 0; k < 4; ++k) b4[k] = conv_b[k];

    const float2* xsrc = (const float2*)(xe_all + (size_t)(sb * LL) * DD);
    for (int e = tid; e < LL * DD / 2; e += 512)
        ((float2*)xe_s)[e] = xsrc[e];
    __syncthreads();

    if (tid < LL * 12) {
        int t = tid / 12, k = tid - t * 12;
        int g = k / 3, kw = k - g * 3;
        int base = 2 * i - 1;
        float s = 0.f;
        #pragma unroll
        for (int kh = 0; kh < 4; ++kh) {
            int r = base + kh;
            if (r >= 0) s = fmaf(wls[g * 12 + kh * 3 + kw], xe_s[t][r], s);
        }
        U[t][k] = s * inv_all[sb * LL + t];
    }
    __syncthreads();

    // bf16 round for internal gate scratch (validated path)
    auto f2bf = [](float f) -> u16 {
        union { float f; unsigned u; } v; v.f = f;
        unsigned u = v.u; u += 0x7fff + ((u >> 16) & 1); return (u16)(u >> 16);
    };
    auto bf2f = [](u16 b) -> float {
        union { unsigned u; float f; } v; v.u = ((unsigned)b) << 16; return v.f;
    };

    #pragma unroll
    for (int k5 = 0; k5 < 5; ++k5) {
        const int t = t0 + 8 * k5;
        float4 u0 = *(const float4*)&U[t][0];
        float4 u1 = *(const float4*)&U[t][4];
        float4 u2 = *(const float4*)&U[t][8];
        float xl = cp > 0 ? xe_s[t][c0 - 1] : 0.f;
        float xm = xe_s[t][c0];
        float xr = xe_s[t][c0 + 1];
        float x2 = cp < 63 ? xe_s[t][c0 + 2] : 0.f;
        float a0 = fmaf(u0.x, xl, fmaf(u0.y, xm, fmaf(u0.z, xr, b4[0])));
        float a1 = fmaf(u0.w, xl, fmaf(u1.x, xm, fmaf(u1.y, xr, b4[1])));
        float a2 = fmaf(u1.z, xl, fmaf(u1.w, xm, fmaf(u2.x, xr, b4[2])));
        float a3 = fmaf(u2.y, xl, fmaf(u2.z, xm, fmaf(u2.w, xr, b4[3])));
        float d0 = fmaf(u0.x, xm, fmaf(u0.y, xr, fmaf(u0.z, x2, b4[0])));
        float d1 = fmaf(u0.w, xm, fmaf(u1.x, xr, fmaf(u1.y, x2, b4[1])));
        float d2 = fmaf(u1.z, xm, fmaf(u1.w, xr, fmaf(u2.x, x2, b4[2])));
        float d3 = fmaf(u2.y, xm, fmaf(u2.z, xr, fmaf(u2.w, x2, b4[3])));
        float fg0 = sigm(a0), ic0 = sigm(a1) * tanhs(a3), og0 = sigm(a2);
        float fg1 = sigm(d0), ic1 = sigm(d1) * tanhs(d3), og1 = sigm(d2);
        u32 f0 = (u32)f2bf(fg0) | ((u32)f2bf(og0) << 16);
        u32 f1 = (u32)f2bf(fg1) | ((u32)f2bf(og1) << 16);
        *(uint2*)&gfo_l[t][c0] = make_uint2(f0, f1);
        gic_l[t][cp] = (u32)f2bf(ic0) | ((u32)f2bf(ic1) << 16);
    }
    __syncthreads();

    if (tid < DD) {                   // in-block scan (f32), h stored as f16
        const int c = tid;
        u16* hp = h1 + SLAB + (size_t)sb * PLANE + (size_t)i * DD + c;
        float cc = 0.f;
        #pragma unroll 4
        for (int t = 0; t < LL; ++t) {
            u32 v = gfo_l[t][c];
            u32 icp = gic_l[t][c >> 1];
            float fg = bf2f((u16)v), og = bf2f((u16)(v >> 16));
            float ic = bf2f((u16)(icp >> ((c & 1) * 16)));
            cc = fmaf(fg, cc, ic);
            *hp = f2h(og * tanhs(cc));
            hp += SLAB;
        }
    }
}

// ---------------- fused level: packed-f16 gates (t-parallel, LDS scratch) + scan ----------------
// 1-D swizzled grid (nr*NSB) x 512. Block: output row i = r0 + (logical % nr), sb = logical / nr.
// px-pair per thread in half2 lanes (x=px0, y=px1). Conv = 48 v_pk_fma_f16.
__global__ __launch_bounds__(512, 4)
void fused_level_kernel(const float* __restrict__ xe_all, const float* __restrict__ inv_all,
                        const u16* __restrict__ xt_h1,   // layer1: h1; layer0: null (density)
                        u16* __restrict__ h_own,
                        float* __restrict__ pool,        // layer1 only
                        const float* __restrict__ conv_w, const float* __restrict__ conv_b,
                        int layer, int r0, int nr) {
    const int nchunk = (nr * NSB) / 8;
    const int logical = ((int)blockIdx.x % 8) * nchunk + (int)blockIdx.x / 8;
    const int i  = r0 + logical % nr;
    const int sb = logical / nr;
    const int tid = threadIdx.x;
    const int cp = tid & 63;
    const int t0 = tid >> 6;          // 0..7 (wave-uniform)
    const int c0 = 2 * cp;

    __shared__ u32 gf_l[LL][DD / 2];  // fg half2 px-pairs   (10.25 KB)
    __shared__ u32 go_l[LL][DD / 2];  // og half2 px-pairs
    __shared__ u32 gi_l[LL][DD / 2];  // ic half2 px-pairs

    __half2 wb[48];                   // wave-uniform -> SGPR-resident broadcasts
    #pragma unroll
    for (int k = 0; k < 48; ++k) wb[k] = __float2half2_rn(conv_w[layer * 48 + k]);
    __half2 bb[4];
    #pragma unroll
    for (int k = 0; k < 4; ++k) bb[k] = __float2half2_rn(conv_b[layer * 4 + k]);
    const __half2 one2 = __float2half2_rn(1.f);
    const __half2 two2 = __float2half2_rn(2.f);
    const __half2 none2 = __float2half2_rn(-1.f);

    const u16* sp[4];
    bool dens[4];
    int wrow[4];
    #pragma unroll
    for (int kh = 0; kh < 4; ++kh) {
        const int wr = 2 * i - 1 + kh;
        wrow[kh] = wr;
        dens[kh] = false;
        sp[kh] = nullptr;
        if (wr >= 0 && wr < 2 * DD) {
            if (wr < DD) {
                if (layer == 0) dens[kh] = true;
                else sp[kh] = xt_h1 + (size_t)(t0 + 1) * SLAB + (size_t)sb * PLANE + (size_t)wr * DD;
            } else {
                sp[kh] = h_own + (size_t)t0 * SLAB + (size_t)sb * PLANE + (size_t)(wr - DD) * DD;
            }
        }
    }
    const bool cL = (cp > 0), cR = (cp < 63);
    const u32 maskA = cL ? 0xFFFFFFFFu : 0xFFFF0000u;   // zero vA at left edge
    const u32 maskC = cR ? 0xFFFFFFFFu : 0x0000FFFFu;   // zero vC at right edge
    const bool anyd = (layer == 0) && (2 * i - 1 < DD);
    const float* xe_u = xe_all + ((size_t)sb * LL + t0) * DD;
    const float* ip   = inv_all + sb * LL + t0;

    for (int k = 0; k < 5; ++k) {
        const int t = t0 + 8 * k;
        __half2 acc0 = bb[0], acc1 = bb[1], acc2 = bb[2], acc3 = bb[3];
        float x_1 = 0.f, xA = 0.f, xB = 0.f, x2 = 0.f, invv = 0.f;
        if (anyd) {
            invv = *ip;
            x_1 = cL ? xe_u[c0 - 1] : 0.f;
            xA = xe_u[c0]; xB = xe_u[c0 + 1];
            x2 = cR ? xe_u[c0 + 2] : 0.f;
        }
        #pragma unroll
        for (int kh = 0; kh < 4; ++kh) {
            u32 pA, pB, pC;
            bool have = true;
            if (dens[kh]) {
                float p = invv * xe_u[wrow[kh]];
                pA = h2bits(__floats2half2_rn(p * x_1, p * xA));
                pB = h2bits(__floats2half2_rn(p * xA, p * xB));
                pC = h2bits(__floats2half2_rn(p * xB, p * x2));
            } else if (sp[kh]) {
                u32 pb = *(const u32*)(sp[kh] + c0);
                u32 up = __shfl_up(pb, 1);
                u32 dn = __shfl_down(pb, 1);
                pA = __builtin_amdgcn_alignbit(pb, up, 16) & maskA;  // (vA, vB0)
                pB = pb;                                             // (vB0, vB1)
                pC = __builtin_amdgcn_alignbit(dn, pb, 16) & maskC;  // (vB1, vC)
            } else {
                have = false; pA = pB = pC = 0;
            }
            if (have) {
                __half2 hA = bits2h(pA), hB = bits2h(pB), hC = bits2h(pC);
                acc0 = __hfma2(hA, wb[kh*3+0], acc0);
                acc0 = __hfma2(hB, wb[kh*3+1], acc0);
                acc0 = __hfma2(hC, wb[kh*3+2], acc0);
                acc1 = __hfma2(hA, wb[12+kh*3+0], acc1);
                acc1 = __hfma2(hB, wb[12+kh*3+1], acc1);
                acc1 = __hfma2(hC, wb[12+kh*3+2], acc1);
                acc2 = __hfma2(hA, wb[24+kh*3+0], acc2);
                acc2 = __hfma2(hB, wb[24+kh*3+1], acc2);
                acc2 = __hfma2(hC, wb[24+kh*3+2], acc2);
                acc3 = __hfma2(hA, wb[36+kh*3+0], acc3);
                acc3 = __hfma2(hB, wb[36+kh*3+1], acc3);
                acc3 = __hfma2(hC, wb[36+kh*3+2], acc3);
            }
        }
        // packed gate finishing: sigmoid2 / tanh2 via f16 exp+rcp (saturation-safe)
        __half2 e;
        e = h2exp(__hneg2(acc0)); __half2 fg2 = h2rcp(__hadd2(one2, e));
        e = h2exp(__hneg2(acc1)); __half2 ig2 = h2rcp(__hadd2(one2, e));
        e = h2exp(__hneg2(acc2)); __half2 og2 = h2rcp(__hadd2(one2, e));
        e = h2exp(__hneg2(__hadd2(acc3, acc3)));
        __half2 cs2 = __hfma2(two2, h2rcp(__hadd2(one2, e)), none2);
        __half2 ic2 = __hmul2(ig2, cs2);
        gf_l[t][cp] = h2bits(fg2);
        go_l[t][cp] = h2bits(og2);
        gi_l[t][cp] = h2bits(ic2);
        #pragma unroll
        for (int kh = 0; kh < 4; ++kh) if (sp[kh]) sp[kh] += 8 * SLAB;
        if (anyd) { xe_u += 8 * DD; ip += 8; }
    }
    __syncthreads();

    if (tid < DD) {                    // phase 2: f32 scan from f16 gate LDS
        const int c = tid;
        const int sh = (c & 1) * 16;
        u16* hp = h_own + SLAB + (size_t)sb * PLANE + (size_t)i * DD + c;
        float cc = 0.f, pr = -1e30f;
        #pragma unroll 4
        for (int t = 0; t < LL; ++t) {
            float fg = h2f((u16)(gf_l[t][c >> 1] >> sh));
            float og = h2f((u16)(go_l[t][c >> 1] >> sh));
            float ic = h2f((u16)(gi_l[t][c >> 1] >> sh));
            cc = fmaf(fg, cc, ic);
            float hn = og * tanhs(cc);
            *hp = f2h(hn);
            pr = fmaxf(pr, hn);
            hp += SLAB;
        }
        if (pool) pool[(size_t)sb * PLANE + (size_t)i * DD + c] = pr;
    }
}

// conv+LSTM update for one tail pixel from the LDS window
__device__ __forceinline__
float tail_px(const float (*wp)[130], const float* wls, const float* bls,
              int lr, int c, float& creg, float& pr) {
    float a0 = bls[0], a1 = bls[1], a2 = bls[2], a3 = bls[3];
    #pragma unroll
    for (int kh = 0; kh < 4; ++kh) {
        #pragma unroll
        for (int kw = 0; kw < 3; ++kw) {
            float v = wp[lr + kh][c + kw];
            a0 = fmaf(v, wls[kh*3+kw], a0);
            a1 = fmaf(v, wls[12+kh*3+kw], a1);
            a2 = fmaf(v, wls[24+kh*3+kw], a2);
            a3 = fmaf(v, wls[36+kh*3+kw], a3);
        }
    }
    float fg = sigm(a0), ig = sigm(a1), og = sigm(a2), cs = tanhs(a3);
    creg = fg * creg + ig * cs;
    float hn = og * tanhs(creg);
    pr = fmaxf(pr, hn);
    return hn;
}

// ---------------- tail rows 123..127: serial t, 5 rows, prefetched staging ----------------
__global__ __launch_bounds__(640)
void tail5_kernel(const u16* __restrict__ hsrc, u16* __restrict__ hdst,
                  float* __restrict__ pool,
                  const float* __restrict__ conv_w, const float* __restrict__ conv_b,
                  int layer) {
    const int sb = blockIdx.x;
    const int tid = threadIdx.x;
    const int slot = tid >> 7;         // 0..4 -> row 123+slot
    const int c = tid & 127;
    const int r = 123 + slot;
    __shared__ float win[2][12][130];  // data at [c+1]; col pads + lr 11 stay zero
    __shared__ float wls[48], bls[4];
    if (tid < 48) wls[tid] = conv_w[layer * 48 + tid];
    if (tid < 4)  bls[tid] = conv_b[layer * 4 + tid];
    for (int e = tid; e < 2 * 12 * 130; e += 640) ((float*)win)[e] = 0.f;

    const bool ldr = tid < 384;        // 6 rows x 64 col-pairs
    const int lrow = tid >> 6;         // 0..5
    const int lcp = tid & 63;
    const u16* gsrc = hsrc + (size_t)sb * PLANE + (size_t)(117 + lrow) * DD + 2 * lcp;
    u32 pre = 0;
    if (ldr) pre = *(const u32*)gsrc;  // t=0: slab 0 (zeroed)

    const int lr0 = 2 * slot;          // window start row for output r
    u16* hd = hdst ? hdst + SLAB + (size_t)sb * PLANE + (size_t)r * DD + c : nullptr;
    float creg = 0.f, pr = -1e30f;

    for (int t = 0; t < LL; ++t) {
        const int p = t & 1;
        __syncthreads();               // prior reads/writes of win[p] done
        if (ldr) {
            win[p][lrow][2 * lcp + 1] = h2f((u16)pre);
            win[p][lrow][2 * lcp + 2] = h2f((u16)(pre >> 16));
        }
        __syncthreads();
        if (ldr && t + 1 < LL)         // prefetch next step's rows (hides HBM latency)
            pre = *(const u32*)(gsrc + (size_t)(t + 1) * SLAB);
        float hn = tail_px(win[p], wls, bls, lr0, c, creg, pr);
        win[p ^ 1][6 + slot][c + 1] = hn;   // own h for t+1's window
        if (hd) { *hd = f2h(hn); hd += SLAB; }
    }
    if (pool) pool[(size_t)sb * PLANE + (size_t)r * DD + c] = pr;
}

// ---------------- final: linear + log_softmax ----------------
__global__ void final_kernel(const float* __restrict__ pool,
                             const float* __restrict__ lin_w,
                             const float* __restrict__ lin_b,
                             float* __restrict__ out) {
    const int b = blockIdx.x;
    const int tid = threadIdx.x;  // 256
    const int DD2 = DD * DD;
    const float* pq = pool + (size_t)b * DD2;
    const float* pa = pool + (size_t)(BB + b) * DD2;
    float s0 = 0.f, s1 = 0.f;
    for (int j = tid; j < DD2; j += 256) {
        float vq = pq[j], va = pa[j];
        s0 += vq * lin_w[j]           + va * lin_w[DD2 + j];
        s1 += vq * lin_w[2 * DD2 + j] + va * lin_w[3 * DD2 + j];
    }
    #pragma unroll
    for (int o = 32; o; o >>= 1) {
        s0 += __shfl_down(s0, o);
        s1 += __shfl_down(s1, o);
    }
    __shared__ float sh0[4], sh1[4];
    int wid = tid >> 6, lane = tid & 63;
    if (lane == 0) { sh0[wid] = s0; sh1[wid] = s1; }
    __syncthreads();
    if (tid == 0) {
        float a0 = sh0[0] + sh0[1] + sh0[2] + sh0[3] + lin_b[0];
        float a1 = sh1[0] + sh1[1] + sh1[2] + sh1[3] + lin_b[1];
        float m = fmaxf(a0, a1);
        float lse = m + logf(expf(a0 - m) + expf(a1 - m));
        out[b * 2 + 0] = a0 - lse;
        out[b * 2 + 1] = a1 - lse;
    }
}

extern "C" void kernel_launch(void* const* d_in, const int* in_sizes, int n_in,
                              void* d_out, int out_size, void* d_ws, size_t ws_size,
                              hipStream_t stream) {
    const int*   q      = (const int*)d_in[0];
    const int*   a      = (const int*)d_in[1];
    const float* embed  = (const float*)d_in[2];
    const float* conv_w = (const float*)d_in[3];
    const float* conv_b = (const float*)d_in[4];
    const float* lin_w  = (const float*)d_in[5];
    const float* lin_b  = (const float*)d_in[6];
    float* out = (float*)d_out;

    // ws: pool 4.2 | xe 1.31 | inv | h1 86 (41 f16 slabs) | h2 86  => ~178 MB
    float* ws      = (float*)d_ws;
    float* pool    = ws;
    float* xe_all  = pool + (size_t)NSB * PLANE;
    float* inv_all = xe_all + (size_t)NU * DD;
    u16*   h1      = (u16*)(inv_all + NU);
    u16*   h2      = h1 + (size_t)(LL + 1) * SLAB;

    // zero the t = -1 slabs
    hipMemsetAsync(h1, 0, SLAB * sizeof(u16), stream);
    hipMemsetAsync(h2, 0, SLAB * sizeof(u16), stream);

    prep_kernel<<<(NU + 3) / 4, 256, 0, stream>>>(q, a, embed, xe_all, inv_all);

    // Levels [0,63) [63,95) [95,111) [111,119) [119,123); rows 123..127 serial tail.
    const int levr[5][2] = {{0,63},{63,32},{95,16},{111,8},{119,4}};

    for (int layer = 0; layer < 2; ++layer) {
        const u16* xt = layer ? h1 : nullptr;
        u16* hh       = layer ? h2 : h1;
        float* pl     = layer ? pool : nullptr;
        for (int k = 0; k < 5; ++k) {
            const int r0 = levr[k][0], nr = levr[k][1];
            if (layer == 0 && k == 0) {
                sep0_kernel<<<63 * NSB, 512, 0, stream>>>(
                    xe_all, inv_all, conv_w, conv_b, h1);
            } else {
                fused_level_kernel<<<nr * NSB, 512, 0, stream>>>(
                    xe_all, inv_all, xt, hh, pl, conv_w, conv_b, layer, r0, nr);
            }
        }
        tail5_kernel<<<NSB, 640, 0, stream>>>(hh, layer ? nullptr : h1,
                                              pl, conv_w, conv_b, layer);
    }

    final_kernel<<<BB, 256, 0, stream>>>(pool, lin_w, lin_b, out);
}

// Round 18
// 464.865 us; speedup vs baseline: 1.0825x; 1.0825x over previous
//
#include <hip/hip_runtime.h>
#include <math.h>

#define BB 32
#define LL 40
#define DD 128
#define NSB 64                        // 2 seq * 32 batch
#define NU  (NSB * LL)                // 2560
#define PLANE (DD * DD)               // 16384
#define SLAB ((size_t)NSB * PLANE)    // u16 elements per t-slab (2 MB)

typedef unsigned short u16;
typedef unsigned int u32;

__device__ __forceinline__ u16 f2bf(float f) {
    union { float f; unsigned u; } v; v.f = f;
    unsigned u = v.u;
    u += 0x7fff + ((u >> 16) & 1);    // RNE
    return (u16)(u >> 16);
}
__device__ __forceinline__ float bf2f(u16 b) {
    union { unsigned u; float f; } v; v.u = ((unsigned)b) << 16;
    return v.f;
}
// Fast math: v_rcp_f32 instead of the IEEE div sequence (~10 instrs saved per call).
// Outputs are bf16-rounded anyway; ~1 ulp rcp error is invisible vs 2e-2 threshold.
__device__ __forceinline__ float rcpf(float x) { return __builtin_amdgcn_rcpf(x); }
__device__ __forceinline__ float sigm(float x)  { return rcpf(1.f + __expf(-x)); }
// tanh(x) = 2*sigmoid(2x)-1 ; exp->inf => rcp->0 => -1 (correct limit)
__device__ __forceinline__ float tanhs(float x) { return fmaf(2.f, rcpf(1.f + __expf(-2.f * x)), -1.f); }

// ---------------- prep: xe rows + inverse squared norms ----------------
__global__ void prep_kernel(const int* __restrict__ q, const int* __restrict__ a,
                            const float* __restrict__ embed,
                            float* __restrict__ xe_all, float* __restrict__ inv_all) {
    int u = blockIdx.x * 4 + (threadIdx.x >> 6);
    int lane = threadIdx.x & 63;
    if (u >= NU) return;
    int sb = u / LL, t = u % LL;
    int s = sb >> 5, b = sb & 31;
    const int* idx = s ? a : q;
    int e = idx[b * LL + t];
    const float* row = embed + (size_t)e * DD;
    float v0 = row[lane], v1 = row[lane + 64];
    xe_all[(size_t)u * DD + lane] = v0;
    xe_all[(size_t)u * DD + lane + 64] = v1;
    float d = v0 * v0 + v1 * v1;
    #pragma unroll
    for (int o = 32; o; o >>= 1) d += __shfl_down(d, o);
    if (lane == 0) inv_all[u] = 1.f / (d + 1e-4f);
}

// ---------------- layer1 rows 0..62: separable density gates + in-block scan ----------------
// 1-D swizzled grid (63*NSB) x 512. Block: one output row i of one sb, all 40 t.
// Density input is rank-1: gate = b + sum_kw U'[t][g*3+kw] * xe[t][c-1+kw],
// U'[t][k] = inv[t] * sum_kh w[g][kh][kw] * xe[t][2i-1+kh]  -> 12 FMA per px.
// NOTE: conv weights live in LDS (wls) because the U-computation indexes them at
// RUNTIME — a per-thread w[48] array would spill to scratch (396 MB of traffic).
__global__ __launch_bounds__(512)
void sep0_kernel(const float* __restrict__ xe_all, const float* __restrict__ inv_all,
                 const float* __restrict__ conv_w, const float* __restrict__ conv_b,
                 u16* __restrict__ h1) {
    const int nchunk = (63 * NSB) / 8;
    const int logical = ((int)blockIdx.x % 8) * nchunk + (int)blockIdx.x / 8;
    const int i  = logical % 63;
    const int sb = logical / 63;
    const int tid = threadIdx.x;
    const int cp = tid & 63;
    const int t0 = tid >> 6;          // 0..7, wave-uniform
    const int c0 = 2 * cp;

    __shared__ float xe_s[LL][DD];    // 20.5 KB
    __shared__ float U[LL][12];       // 1.9 KB (rows 48B -> 16B aligned)
    __shared__ u32 gfo_l[LL][DD];     // 20.5 KB
    __shared__ u32 gic_l[LL][DD / 2]; // 10.25 KB
    __shared__ float wls[48];

    if (tid < 48) wls[tid] = conv_w[tid];
    float b4[4];
    #pragma unroll
    for (int k = 0; k < 4; ++k) b4[k] = conv_b[k];

    // stage all 40 xe rows (float2 coalesced)
    const float2* xsrc = (const float2*)(xe_all + (size_t)(sb * LL) * DD);
    for (int e = tid; e < LL * DD / 2; e += 512)
        ((float2*)xe_s)[e] = xsrc[e];
    __syncthreads();                  // xe_s + wls ready

    // U'[t][k] with inv folded in (runtime-indexed weights -> LDS read)
    if (tid < LL * 12) {
        int t = tid / 12, k = tid - t * 12;
        int g = k / 3, kw = k - g * 3;
        int base = 2 * i - 1;
        float s = 0.f;
        #pragma unroll
        for (int kh = 0; kh < 4; ++kh) {
            int r = base + kh;
            if (r >= 0) s = fmaf(wls[g * 12 + kh * 3 + kw], xe_s[t][r], s);
        }
        U[t][k] = s * inv_all[sb * LL + t];
    }
    __syncthreads();

    #pragma unroll
    for (int k5 = 0; k5 < 5; ++k5) {
        const int t = t0 + 8 * k5;
        float4 u0 = *(const float4*)&U[t][0];
        float4 u1 = *(const float4*)&U[t][4];
        float4 u2 = *(const float4*)&U[t][8];
        float xl = cp > 0 ? xe_s[t][c0 - 1] : 0.f;
        float xm = xe_s[t][c0];
        float xr = xe_s[t][c0 + 1];
        float x2 = cp < 63 ? xe_s[t][c0 + 2] : 0.f;
        // px0 gates (window cols c0-1, c0, c0+1)
        float a0 = fmaf(u0.x, xl, fmaf(u0.y, xm, fmaf(u0.z, xr, b4[0])));
        float a1 = fmaf(u0.w, xl, fmaf(u1.x, xm, fmaf(u1.y, xr, b4[1])));
        float a2 = fmaf(u1.z, xl, fmaf(u1.w, xm, fmaf(u2.x, xr, b4[2])));
        float a3 = fmaf(u2.y, xl, fmaf(u2.z, xm, fmaf(u2.w, xr, b4[3])));
        // px1 gates (cols c0, c0+1, c0+2)
        float d0 = fmaf(u0.x, xm, fmaf(u0.y, xr, fmaf(u0.z, x2, b4[0])));
        float d1 = fmaf(u0.w, xm, fmaf(u1.x, xr, fmaf(u1.y, x2, b4[1])));
        float d2 = fmaf(u1.z, xm, fmaf(u1.w, xr, fmaf(u2.x, x2, b4[2])));
        float d3 = fmaf(u2.y, xm, fmaf(u2.z, xr, fmaf(u2.w, x2, b4[3])));
        float fg0 = sigm(a0), ic0 = sigm(a1) * tanhs(a3), og0 = sigm(a2);
        float fg1 = sigm(d0), ic1 = sigm(d1) * tanhs(d3), og1 = sigm(d2);
        u32 f0 = (u32)f2bf(fg0) | ((u32)f2bf(og0) << 16);
        u32 f1 = (u32)f2bf(fg1) | ((u32)f2bf(og1) << 16);
        *(uint2*)&gfo_l[t][c0] = make_uint2(f0, f1);
        gic_l[t][cp] = (u32)f2bf(ic0) | ((u32)f2bf(ic1) << 16);
    }
    __syncthreads();

    if (tid < DD) {                   // in-block scan
        const int c = tid;
        u16* hp = h1 + SLAB + (size_t)sb * PLANE + (size_t)i * DD + c;
        float cc = 0.f;
        #pragma unroll 4
        for (int t = 0; t < LL; ++t) {
            u32 v = gfo_l[t][c];
            u32 icp = gic_l[t][c >> 1];
            float fg = bf2f((u16)v), og = bf2f((u16)(v >> 16));
            float ic = bf2f((u16)(icp >> ((c & 1) * 16)));
            cc = fg * cc + ic;
            *hp = f2bf(og * tanhs(cc));
            hp += SLAB;
        }
    }
}

// ---------------- fused level: gates (t-parallel, LDS scratch) + in-block scan ----------------
// 1-D swizzled grid (nr*NSB) x 512. Block: output row i = r0 + (logical % nr), sb = logical / nr.
__global__ __launch_bounds__(512, 8)
void fused_level_kernel(const float* __restrict__ xe_all, const float* __restrict__ inv_all,
                        const u16* __restrict__ xt_h1,   // layer1: h1; layer0: null (density)
                        u16* __restrict__ h_own,
                        float* __restrict__ pool,        // layer1 only
                        const float* __restrict__ conv_w, const float* __restrict__ conv_b,
                        int layer, int r0, int nr) {
    const int nchunk = (nr * NSB) / 8;
    const int logical = ((int)blockIdx.x % 8) * nchunk + (int)blockIdx.x / 8;
    const int i  = r0 + logical % nr;
    const int sb = logical / nr;
    const int tid = threadIdx.x;
    const int cp = tid & 63;
    const int t0 = tid >> 6;          // 0..7 (wave-uniform)
    const int c0 = 2 * cp;

    __shared__ u32 gfo_l[LL][DD];     // fg | og<<16, per px      (20.5 KB)
    __shared__ u32 gic_l[LL][DD / 2]; // ic px-pairs              (10.25 KB)

    float w[48], b4[4];               // literal-indexed only (unrolled) -> registers/SGPRs
    #pragma unroll
    for (int k = 0; k < 48; ++k) w[k] = conv_w[layer * 48 + k];
    #pragma unroll
    for (int k = 0; k < 4; ++k) b4[k] = conv_b[layer * 4 + k];

    const u16* sp[4];
    bool dens[4];
    int wrow[4];
    #pragma unroll
    for (int kh = 0; kh < 4; ++kh) {
        const int wr = 2 * i - 1 + kh;
        wrow[kh] = wr;
        dens[kh] = false;
        sp[kh] = nullptr;
        if (wr >= 0 && wr < 2 * DD) {
            if (wr < DD) {
                if (layer == 0) dens[kh] = true;
                else sp[kh] = xt_h1 + (size_t)(t0 + 1) * SLAB + (size_t)sb * PLANE + (size_t)wr * DD;
            } else {
                sp[kh] = h_own + (size_t)t0 * SLAB + (size_t)sb * PLANE + (size_t)(wr - DD) * DD;
            }
        }
    }
    const bool cL = (cp > 0), cR = (cp < 63);
    const bool anyd = (layer == 0) && (2 * i - 1 < DD);
    const float* xe_u = xe_all + ((size_t)sb * LL + t0) * DD;
    const float* ip   = inv_all + sb * LL + t0;

    #pragma unroll
    for (int k = 0; k < 5; ++k) {
        const int t = t0 + 8 * k;
        float a0 = b4[0], a1 = b4[1], a2 = b4[2], a3 = b4[3];   // px0
        float d0 = b4[0], d1 = b4[1], d2 = b4[2], d3 = b4[3];   // px1
        float x_1 = 0.f, xA = 0.f, xB = 0.f, x2 = 0.f, invv = 0.f;
        if (anyd) {
            invv = *ip;
            x_1 = cL ? xe_u[c0 - 1] : 0.f;
            xA = xe_u[c0]; xB = xe_u[c0 + 1];
            x2 = cR ? xe_u[c0 + 2] : 0.f;
        }
        #pragma unroll
        for (int kh = 0; kh < 4; ++kh) {
            float vA, vB0, vB1, vC;   // cols c0-1, c0, c0+1, c0+2 of window row
            if (dens[kh]) {
                float p = invv * xe_u[wrow[kh]];
                vA = p * x_1; vB0 = p * xA; vB1 = p * xB; vC = p * x2;
            } else if (sp[kh]) {
                u32 pb = *(const u32*)(sp[kh] + c0);
                u32 up = __shfl_up(pb, 1);
                u32 dn = __shfl_down(pb, 1);
                vB0 = bf2f((u16)pb); vB1 = bf2f((u16)(pb >> 16));
                vA = cL ? bf2f((u16)(up >> 16)) : 0.f;
                vC = cR ? bf2f((u16)dn) : 0.f;
            } else {
                vA = 0.f; vB0 = 0.f; vB1 = 0.f; vC = 0.f;
            }
            a0 = fmaf(vA,  w[kh*3+0], a0);    a0 = fmaf(vB0, w[kh*3+1], a0);    a0 = fmaf(vB1, w[kh*3+2], a0);
            a1 = fmaf(vA,  w[12+kh*3+0], a1); a1 = fmaf(vB0, w[12+kh*3+1], a1); a1 = fmaf(vB1, w[12+kh*3+2], a1);
            a2 = fmaf(vA,  w[24+kh*3+0], a2); a2 = fmaf(vB0, w[24+kh*3+1], a2); a2 = fmaf(vB1, w[24+kh*3+2], a2);
            a3 = fmaf(vA,  w[36+kh*3+0], a3); a3 = fmaf(vB0, w[36+kh*3+1], a3); a3 = fmaf(vB1, w[36+kh*3+2], a3);
            d0 = fmaf(vB0, w[kh*3+0], d0);    d0 = fmaf(vB1, w[kh*3+1], d0);    d0 = fmaf(vC, w[kh*3+2], d0);
            d1 = fmaf(vB0, w[12+kh*3+0], d1); d1 = fmaf(vB1, w[12+kh*3+1], d1); d1 = fmaf(vC, w[12+kh*3+2], d1);
            d2 = fmaf(vB0, w[24+kh*3+0], d2); d2 = fmaf(vB1, w[24+kh*3+1], d2); d2 = fmaf(vC, w[24+kh*3+2], d2);
            d3 = fmaf(vB0, w[36+kh*3+0], d3); d3 = fmaf(vB1, w[36+kh*3+1], d3); d3 = fmaf(vC, w[36+kh*3+2], d3);
        }
        float fg0 = sigm(a0), ic0 = sigm(a1) * tanhs(a3), og0 = sigm(a2);
        float fg1 = sigm(d0), ic1 = sigm(d1) * tanhs(d3), og1 = sigm(d2);
        u32 f0 = (u32)f2bf(fg0) | ((u32)f2bf(og0) << 16);
        u32 f1 = (u32)f2bf(fg1) | ((u32)f2bf(og1) << 16);
        *(uint2*)&gfo_l[t][c0] = make_uint2(f0, f1);
        gic_l[t][cp] = (u32)f2bf(ic0) | ((u32)f2bf(ic1) << 16);
        #pragma unroll
        for (int kh = 0; kh < 4; ++kh) if (sp[kh]) sp[kh] += 8 * SLAB;
        if (anyd) { xe_u += 8 * DD; ip += 8; }
    }
    __syncthreads();

    if (tid < DD) {                    // phase 2: per-pixel scan from LDS
        const int c = tid;
        u16* hp = h_own + SLAB + (size_t)sb * PLANE + (size_t)i * DD + c;
        float cc = 0.f, pr = -1e30f;
        #pragma unroll 4
        for (int t = 0; t < LL; ++t) {
            u32 v = gfo_l[t][c];
            u32 icp = gic_l[t][c >> 1];
            float fg = bf2f((u16)v), og = bf2f((u16)(v >> 16));
            float ic = bf2f((u16)(icp >> ((c & 1) * 16)));
            cc = fg * cc + ic;
            float hn = og * tanhs(cc);
            *hp = f2bf(hn);
            pr = fmaxf(pr, hn);
            hp += SLAB;
        }
        if (pool) pool[(size_t)sb * PLANE + (size_t)i * DD + c] = pr;
    }
}

// conv+LSTM update for one tail pixel from the LDS window
__device__ __forceinline__
float tail_px(const float (*wp)[130], const float* wls, const float* bls,
              int lr, int c, float& creg, float& pr) {
    float a0 = bls[0], a1 = bls[1], a2 = bls[2], a3 = bls[3];
    #pragma unroll
    for (int kh = 0; kh < 4; ++kh) {
        #pragma unroll
        for (int kw = 0; kw < 3; ++kw) {
            float v = wp[lr + kh][c + kw];
            a0 = fmaf(v, wls[kh*3+kw], a0);
            a1 = fmaf(v, wls[12+kh*3+kw], a1);
            a2 = fmaf(v, wls[24+kh*3+kw], a2);
            a3 = fmaf(v, wls[36+kh*3+kw], a3);
        }
    }
    float fg = sigm(a0), ig = sigm(a1), og = sigm(a2), cs = tanhs(a3);
    creg = fg * creg + ig * cs;
    float hn = og * tanhs(creg);
    pr = fmaxf(pr, hn);
    return hn;
}

// ---------------- tail rows 123..127: serial t, 5 rows, prefetched staging ----------------
__global__ __launch_bounds__(640)
void tail5_kernel(const u16* __restrict__ hsrc, u16* __restrict__ hdst,
                  float* __restrict__ pool,
                  const float* __restrict__ conv_w, const float* __restrict__ conv_b,
                  int layer) {
    const int sb = blockIdx.x;
    const int tid = threadIdx.x;
    const int slot = tid >> 7;         // 0..4 -> row 123+slot
    const int c = tid & 127;
    const int r = 123 + slot;
    __shared__ float win[2][12][130];  // data at [c+1]; col pads + lr 11 stay zero
    __shared__ float wls[48], bls[4];
    if (tid < 48) wls[tid] = conv_w[layer * 48 + tid];
    if (tid < 4)  bls[tid] = conv_b[layer * 4 + tid];
    for (int e = tid; e < 2 * 12 * 130; e += 640) ((float*)win)[e] = 0.f;

    const bool ldr = tid < 384;        // 6 rows x 64 col-pairs
    const int lrow = tid >> 6;         // 0..5
    const int lcp = tid & 63;
    const u16* gsrc = hsrc + (size_t)sb * PLANE + (size_t)(117 + lrow) * DD + 2 * lcp;
    u32 pre = 0;
    if (ldr) pre = *(const u32*)gsrc;  // t=0: slab 0 (zeroed)

    const int lr0 = 2 * slot;          // window start row for output r
    u16* hd = hdst ? hdst + SLAB + (size_t)sb * PLANE + (size_t)r * DD + c : nullptr;
    float creg = 0.f, pr = -1e30f;

    for (int t = 0; t < LL; ++t) {
        const int p = t & 1;
        __syncthreads();               // prior reads/writes of win[p] done
        if (ldr) {
            win[p][lrow][2 * lcp + 1] = bf2f((u16)pre);
            win[p][lrow][2 * lcp + 2] = bf2f((u16)(pre >> 16));
        }
        __syncthreads();
        if (ldr && t + 1 < LL)         // prefetch next step's rows (hides HBM latency)
            pre = *(const u32*)(gsrc + (size_t)(t + 1) * SLAB);
        float hn = tail_px(win[p], wls, bls, lr0, c, creg, pr);
        win[p ^ 1][6 + slot][c + 1] = hn;   // own h for t+1's window
        if (hd) { *hd = f2bf(hn); hd += SLAB; }
    }
    if (pool) pool[(size_t)sb * PLANE + (size_t)r * DD + c] = pr;
}

// ---------------- final: linear + log_softmax ----------------
__global__ void final_kernel(const float* __restrict__ pool,
                             const float* __restrict__ lin_w,
                             const float* __restrict__ lin_b,
                             float* __restrict__ out) {
    const int b = blockIdx.x;
    const int tid = threadIdx.x;  // 256
    const int DD2 = DD * DD;
    const float* pq = pool + (size_t)b * DD2;
    const float* pa = pool + (size_t)(BB + b) * DD2;
    float s0 = 0.f, s1 = 0.f;
    for (int j = tid; j < DD2; j += 256) {
        float vq = pq[j], va = pa[j];
        s0 += vq * lin_w[j]           + va * lin_w[DD2 + j];
        s1 += vq * lin_w[2 * DD2 + j] + va * lin_w[3 * DD2 + j];
    }
    #pragma unroll
    for (int o = 32; o; o >>= 1) {
        s0 += __shfl_down(s0, o);
        s1 += __shfl_down(s1, o);
    }
    __shared__ float sh0[4], sh1[4];
    int wid = tid >> 6, lane = tid & 63;
    if (lane == 0) { sh0[wid] = s0; sh1[wid] = s1; }
    __syncthreads();
    if (tid == 0) {
        float a0 = sh0[0] + sh0[1] + sh0[2] + sh0[3] + lin_b[0];
        float a1 = sh1[0] + sh1[1] + sh1[2] + sh1[3] + lin_b[1];
        float m = fmaxf(a0, a1);
        float lse = m + logf(expf(a0 - m) + expf(a1 - m));
        out[b * 2 + 0] = a0 - lse;
        out[b * 2 + 1] = a1 - lse;
    }
}

extern "C" void kernel_launch(void* const* d_in, const int* in_sizes, int n_in,
                              void* d_out, int out_size, void* d_ws, size_t ws_size,
                              hipStream_t stream) {
    const int*   q      = (const int*)d_in[0];
    const int*   a      = (const int*)d_in[1];
    const float* embed  = (const float*)d_in[2];
    const float* conv_w = (const float*)d_in[3];
    const float* conv_b = (const float*)d_in[4];
    const float* lin_w  = (const float*)d_in[5];
    const float* lin_b  = (const float*)d_in[6];
    float* out = (float*)d_out;

    // ws: pool 4.2 | xe 1.31 | inv | h1 86 (41 bf16 slabs) | h2 86  => ~178 MB
    float* ws      = (float*)d_ws;
    float* pool    = ws;
    float* xe_all  = pool + (size_t)NSB * PLANE;
    float* inv_all = xe_all + (size_t)NU * DD;
    u16*   h1      = (u16*)(inv_all + NU);
    u16*   h2      = h1 + (size_t)(LL + 1) * SLAB;

    // zero the t = -1 slabs
    hipMemsetAsync(h1, 0, SLAB * sizeof(u16), stream);
    hipMemsetAsync(h2, 0, SLAB * sizeof(u16), stream);

    prep_kernel<<<(NU + 3) / 4, 256, 0, stream>>>(q, a, embed, xe_all, inv_all);

    // Levels [0,63) [63,95) [95,111) [111,119) [119,123); rows 123..127 serial tail.
    const int levr[5][2] = {{0,63},{63,32},{95,16},{111,8},{119,4}};

    for (int layer = 0; layer < 2; ++layer) {
        const u16* xt = layer ? h1 : nullptr;
        u16* hh       = layer ? h2 : h1;
        float* pl     = layer ? pool : nullptr;
        for (int k = 0; k < 5; ++k) {
            const int r0 = levr[k][0], nr = levr[k][1];
            if (layer == 0 && k == 0) {
                sep0_kernel<<<63 * NSB, 512, 0, stream>>>(
                    xe_all, inv_all, conv_w, conv_b, h1);
            } else {
                fused_level_kernel<<<nr * NSB, 512, 0, stream>>>(
                    xe_all, inv_all, xt, hh, pl, conv_w, conv_b, layer, r0, nr);
            }
        }
        tail5_kernel<<<NSB, 640, 0, stream>>>(hh, layer ? nullptr : h1,
                                              pl, conv_w, conv_b, layer);
    }

    final_kernel<<<BB, 256, 0, stream>>>(pool, lin_w, lin_b, out);
}

// Round 20
// 450.955 us; speedup vs baseline: 1.1159x; 1.0308x over previous
//
#include <hip/hip_runtime.h>
#include <math.h>

#define BB 32
#define LL 40
#define DD 128
#define NSB 64                        // 2 seq * 32 batch
#define NU  (NSB * LL)                // 2560
#define PLANE (DD * DD)               // 16384
#define SLAB ((size_t)NSB * PLANE)    // u16 elements per t-slab (2 MB)

typedef unsigned short u16;
typedef unsigned int u32;
typedef _Float16 h2t __attribute__((ext_vector_type(2)));
typedef __fp16  p2t __attribute__((ext_vector_type(2)));   // cvt_pkrtz return type

// ---- 16-bit helpers: h state is fp16 (|h|<1 -> fp16 beats bf16 there) ----
__device__ __forceinline__ u16 f2h(float f) {
    union { _Float16 h; u16 u; } v; v.h = (_Float16)f; return v.u;
}
__device__ __forceinline__ float h2f(u16 b) {
    union { u16 u; _Float16 h; } v; v.u = b; return (float)v.h;
}
__device__ __forceinline__ h2t b2h(u32 b) {
    union { u32 u; h2t h; } v; v.u = b; return v.h;
}
__device__ __forceinline__ u32 pk16(float x, float y) {   // v_cvt_pkrtz_f16_f32
    union { p2t h; u32 u; } v; v.h = __builtin_amdgcn_cvt_pkrtz(x, y); return v.u;
}
// packed f16 dot2 with f32 accumulate: D = a.x*b.x + a.y*b.y + c
__device__ __forceinline__ float fdot2(u32 a, u32 b, float c) {
    return __builtin_amdgcn_fdot2(b2h(a), b2h(b), c, false);
}

// bf16 (gate LDS scratch only)
__device__ __forceinline__ u16 f2bf(float f) {
    union { float f; unsigned u; } v; v.f = f;
    unsigned u = v.u;
    u += 0x7fff + ((u >> 16) & 1);    // RNE
    return (u16)(u >> 16);
}
__device__ __forceinline__ float bf2f(u16 b) {
    union { unsigned u; float f; } v; v.u = ((unsigned)b) << 16;
    return v.f;
}
// Fast math: v_rcp_f32 instead of the IEEE div sequence.
__device__ __forceinline__ float rcpf(float x) { return __builtin_amdgcn_rcpf(x); }
__device__ __forceinline__ float sigm(float x)  { return rcpf(1.f + __expf(-x)); }
__device__ __forceinline__ float tanhs(float x) { return fmaf(2.f, rcpf(1.f + __expf(-2.f * x)), -1.f); }

// ---------------- prep: xe rows + inverse squared norms ----------------
__global__ void prep_kernel(const int* __restrict__ q, const int* __restrict__ a,
                            const float* __restrict__ embed,
                            float* __restrict__ xe_all, float* __restrict__ inv_all) {
    int u = blockIdx.x * 4 + (threadIdx.x >> 6);
    int lane = threadIdx.x & 63;
    if (u >= NU) return;
    int sb = u / LL, t = u % LL;
    int s = sb >> 5, b = sb & 31;
    const int* idx = s ? a : q;
    int e = idx[b * LL + t];
    const float* row = embed + (size_t)e * DD;
    float v0 = row[lane], v1 = row[lane + 64];
    xe_all[(size_t)u * DD + lane] = v0;
    xe_all[(size_t)u * DD + lane + 64] = v1;
    float d = v0 * v0 + v1 * v1;
    #pragma unroll
    for (int o = 32; o; o >>= 1) d += __shfl_down(d, o);
    if (lane == 0) inv_all[u] = 1.f / (d + 1e-4f);
}

// ---------------- pack conv weights into f16 dot2 pairs ----------------
// pw[l*48 + kh*12 + g*3 + s]: s=0 -> (w0,w1); s=1 -> (w2,0); s=2 -> (0,w2)
__global__ void packw_kernel(const float* __restrict__ conv_w, u32* __restrict__ pw) {
    int id = threadIdx.x;
    if (id >= 96) return;
    int l = id / 48, r = id - l * 48;
    int kh = r / 12, g = (r - kh * 12) / 3, s = r % 3;
    const float* w = conv_w + l * 48 + g * 12 + kh * 3;
    float x, y;
    if (s == 0)      { x = w[0]; y = w[1]; }
    else if (s == 1) { x = w[2]; y = 0.f; }
    else             { x = 0.f;  y = w[2]; }
    pw[id] = (u32)f2h(x) | ((u32)f2h(y) << 16);   // RNE per element
}

// ---------------- layer1 rows 0..62: separable density gates + in-block scan ----------------
// 1-D swizzled grid (63*NSB) x 512. Block: one output row i of one sb, all 40 t.
// NOTE: conv weights live in LDS (wls) because the U-computation indexes them at
// RUNTIME — a per-thread w[48] array would spill to scratch (396 MB of traffic).
__global__ __launch_bounds__(512)
void sep0_kernel(const float* __restrict__ xe_all, const float* __restrict__ inv_all,
                 const float* __restrict__ conv_w, const float* __restrict__ conv_b,
                 u16* __restrict__ h1) {
    const int nchunk = (63 * NSB) / 8;
    const int logical = ((int)blockIdx.x % 8) * nchunk + (int)blockIdx.x / 8;
    const int i  = logical % 63;
    const int sb = logical / 63;
    const int tid = threadIdx.x;
    const int cp = tid & 63;
    const int t0 = tid >> 6;          // 0..7, wave-uniform
    const int c0 = 2 * cp;

    __shared__ float xe_s[LL][DD];    // 20.5 KB
    __shared__ float U[LL][12];
    __shared__ u32 gfo_l[LL][DD];     // bf16-packed internal gate scratch
    __shared__ u32 gic_l[LL][DD / 2];
    __shared__ float wls[48];

    if (tid < 48) wls[tid] = conv_w[tid];
    float b4[4];
    #pragma unroll
    for (int k = 0; k < 4; ++k) b4[k] = conv_b[k];

    const float2* xsrc = (const float2*)(xe_all + (size_t)(sb * LL) * DD);
    for (int e = tid; e < LL * DD / 2; e += 512)
        ((float2*)xe_s)[e] = xsrc[e];
    __syncthreads();

    if (tid < LL * 12) {
        int t = tid / 12, k = tid - t * 12;
        int g = k / 3, kw = k - g * 3;
        int base = 2 * i - 1;
        float s = 0.f;
        #pragma unroll
        for (int kh = 0; kh < 4; ++kh) {
            int r = base + kh;
            if (r >= 0) s = fmaf(wls[g * 12 + kh * 3 + kw], xe_s[t][r], s);
        }
        U[t][k] = s * inv_all[sb * LL + t];
    }
    __syncthreads();

    #pragma unroll
    for (int k5 = 0; k5 < 5; ++k5) {
        const int t = t0 + 8 * k5;
        float4 u0 = *(const float4*)&U[t][0];
        float4 u1 = *(const float4*)&U[t][4];
        float4 u2 = *(const float4*)&U[t][8];
        float xl = cp > 0 ? xe_s[t][c0 - 1] : 0.f;
        float xm = xe_s[t][c0];
        float xr = xe_s[t][c0 + 1];
        float x2 = cp < 63 ? xe_s[t][c0 + 2] : 0.f;
        float a0 = fmaf(u0.x, xl, fmaf(u0.y, xm, fmaf(u0.z, xr, b4[0])));
        float a1 = fmaf(u0.w, xl, fmaf(u1.x, xm, fmaf(u1.y, xr, b4[1])));
        float a2 = fmaf(u1.z, xl, fmaf(u1.w, xm, fmaf(u2.x, xr, b4[2])));
        float a3 = fmaf(u2.y, xl, fmaf(u2.z, xm, fmaf(u2.w, xr, b4[3])));
        float d0 = fmaf(u0.x, xm, fmaf(u0.y, xr, fmaf(u0.z, x2, b4[0])));
        float d1 = fmaf(u0.w, xm, fmaf(u1.x, xr, fmaf(u1.y, x2, b4[1])));
        float d2 = fmaf(u1.z, xm, fmaf(u1.w, xr, fmaf(u2.x, x2, b4[2])));
        float d3 = fmaf(u2.y, xm, fmaf(u2.z, xr, fmaf(u2.w, x2, b4[3])));
        float fg0 = sigm(a0), ic0 = sigm(a1) * tanhs(a3), og0 = sigm(a2);
        float fg1 = sigm(d0), ic1 = sigm(d1) * tanhs(d3), og1 = sigm(d2);
        u32 f0 = (u32)f2bf(fg0) | ((u32)f2bf(og0) << 16);
        u32 f1 = (u32)f2bf(fg1) | ((u32)f2bf(og1) << 16);
        *(uint2*)&gfo_l[t][c0] = make_uint2(f0, f1);
        gic_l[t][cp] = (u32)f2bf(ic0) | ((u32)f2bf(ic1) << 16);
    }
    __syncthreads();

    if (tid < DD) {                   // in-block scan; h stored f16
        const int c = tid;
        u16* hp = h1 + SLAB + (size_t)sb * PLANE + (size_t)i * DD + c;
        float cc = 0.f;
        #pragma unroll 4
        for (int t = 0; t < LL; ++t) {
            u32 v = gfo_l[t][c];
            u32 icp = gic_l[t][c >> 1];
            float fg = bf2f((u16)v), og = bf2f((u16)(v >> 16));
            float ic = bf2f((u16)(icp >> ((c & 1) * 16)));
            cc = fg * cc + ic;
            *hp = f2h(og * tanhs(cc));
            hp += SLAB;
        }
    }
}

// ---------------- fused level: dot2-f16 gates (t-parallel, LDS scratch) + scan ----------------
// 1-D swizzled grid (nr*NSB) x 512. Block: output row i = r0 + (logical % nr), sb = logical / nr.
// Conv: per gate/kh/px-pair = 4 chained v_dot2_f32_f16 with SGPR-resident packed weights.
__global__ __launch_bounds__(512, 8)
void fused_level_kernel(const float* __restrict__ xe_all, const float* __restrict__ inv_all,
                        const u16* __restrict__ xt_h1,   // layer1: h1; layer0: null (density)
                        u16* __restrict__ h_own,
                        float* __restrict__ pool,        // layer1 only
                        const u32* __restrict__ pw,      // packed f16 weight pairs
                        const float* __restrict__ conv_b,
                        int layer, int r0, int nr) {
    const int nchunk = (nr * NSB) / 8;
    const int logical = ((int)blockIdx.x % 8) * nchunk + (int)blockIdx.x / 8;
    const int i  = r0 + logical % nr;
    const int sb = logical / nr;
    const int tid = threadIdx.x;
    const int cp = tid & 63;
    const int t0 = tid >> 6;          // 0..7 (wave-uniform)
    const int c0 = 2 * cp;

    __shared__ u32 gfo_l[LL][DD];     // fg | og<<16, per px      (20.5 KB)
    __shared__ u32 gic_l[LL][DD / 2]; // ic px-pairs              (10.25 KB)

    u32 uwp[48];                      // uniform, literal-indexed -> SGPRs
    #pragma unroll
    for (int k = 0; k < 48; ++k) uwp[k] = pw[layer * 48 + k];
    float b4[4];
    #pragma unroll
    for (int k = 0; k < 4; ++k) b4[k] = conv_b[layer * 4 + k];

    const u16* sp[4];
    bool dens[4];
    int wrow[4];
    #pragma unroll
    for (int kh = 0; kh < 4; ++kh) {
        const int wr = 2 * i - 1 + kh;
        wrow[kh] = wr;
        dens[kh] = false;
        sp[kh] = nullptr;
        if (wr >= 0 && wr < 2 * DD) {
            if (wr < DD) {
                if (layer == 0) dens[kh] = true;
                else sp[kh] = xt_h1 + (size_t)(t0 + 1) * SLAB + (size_t)sb * PLANE + (size_t)wr * DD;
            } else {
                sp[kh] = h_own + (size_t)t0 * SLAB + (size_t)sb * PLANE + (size_t)(wr - DD) * DD;
            }
        }
    }
    const bool cL = (cp > 0), cR = (cp < 63);
    const u32 maskA = cL ? 0xFFFFFFFFu : 0xFFFF0000u;   // zero vA at left edge
    const u32 maskC = cR ? 0xFFFFFFFFu : 0x0000FFFFu;   // zero vC at right edge
    const bool anyd = (layer == 0) && (2 * i - 1 < DD);
    const float* xe_u = xe_all + ((size_t)sb * LL + t0) * DD;
    const float* ip   = inv_all + sb * LL + t0;

    #pragma unroll
    for (int k = 0; k < 5; ++k) {
        const int t = t0 + 8 * k;
        float a0 = b4[0], a1 = b4[1], a2 = b4[2], a3 = b4[3];   // px0
        float d0 = b4[0], d1 = b4[1], d2 = b4[2], d3 = b4[3];   // px1
        float x_1 = 0.f, xA = 0.f, xB = 0.f, x2 = 0.f, invv = 0.f;
        if (anyd) {
            invv = *ip;
            x_1 = cL ? xe_u[c0 - 1] : 0.f;
            xA = xe_u[c0]; xB = xe_u[c0 + 1];
            x2 = cR ? xe_u[c0 + 2] : 0.f;
        }
        #pragma unroll
        for (int kh = 0; kh < 4; ++kh) {
            u32 pA, pB, pC;           // packed f16: (vA,vB0), (vB0,vB1), (vB1,vC)
            if (dens[kh]) {
                float p = invv * xe_u[wrow[kh]];
                pA = pk16(p * x_1, p * xA);
                pB = pk16(p * xA, p * xB);
                pC = pk16(p * xB, p * x2);
            } else if (sp[kh]) {
                u32 pb = *(const u32*)(sp[kh] + c0);
                u32 up = __shfl_up(pb, 1);
                u32 dn = __shfl_down(pb, 1);
                pA = __builtin_amdgcn_alignbit(pb, up, 16) & maskA;
                pB = pb;
                pC = __builtin_amdgcn_alignbit(dn, pb, 16) & maskC;
            } else {
                pA = pB = pC = 0;
            }
            const int wbase = kh * 12;
            // px0: vA*w0 + vB0*w1 + vB1*w2 ; px1: vB0*w0 + vB1*w1 + vC*w2
            a0 = fdot2(pA, uwp[wbase + 0], a0);  a0 = fdot2(pC, uwp[wbase + 1], a0);
            d0 = fdot2(pB, uwp[wbase + 0], d0);  d0 = fdot2(pC, uwp[wbase + 2], d0);
            a1 = fdot2(pA, uwp[wbase + 3], a1);  a1 = fdot2(pC, uwp[wbase + 4], a1);
            d1 = fdot2(pB, uwp[wbase + 3], d1);  d1 = fdot2(pC, uwp[wbase + 5], d1);
            a2 = fdot2(pA, uwp[wbase + 6], a2);  a2 = fdot2(pC, uwp[wbase + 7], a2);
            d2 = fdot2(pB, uwp[wbase + 6], d2);  d2 = fdot2(pC, uwp[wbase + 8], d2);
            a3 = fdot2(pA, uwp[wbase + 9], a3);  a3 = fdot2(pC, uwp[wbase + 10], a3);
            d3 = fdot2(pB, uwp[wbase + 9], d3);  d3 = fdot2(pC, uwp[wbase + 11], d3);
        }
        float fg0 = sigm(a0), ic0 = sigm(a1) * tanhs(a3), og0 = sigm(a2);
        float fg1 = sigm(d0), ic1 = sigm(d1) * tanhs(d3), og1 = sigm(d2);
        u32 f0 = (u32)f2bf(fg0) | ((u32)f2bf(og0) << 16);
        u32 f1 = (u32)f2bf(fg1) | ((u32)f2bf(og1) << 16);
        *(uint2*)&gfo_l[t][c0] = make_uint2(f0, f1);
        gic_l[t][cp] = (u32)f2bf(ic0) | ((u32)f2bf(ic1) << 16);
        #pragma unroll
        for (int kh = 0; kh < 4; ++kh) if (sp[kh]) sp[kh] += 8 * SLAB;
        if (anyd) { xe_u += 8 * DD; ip += 8; }
    }
    __syncthreads();

    if (tid < DD) {                    // phase 2: per-pixel scan from LDS; h stored f16
        const int c = tid;
        u16* hp = h_own + SLAB + (size_t)sb * PLANE + (size_t)i * DD + c;
        float cc = 0.f, pr = -1e30f;
        #pragma unroll 4
        for (int t = 0; t < LL; ++t) {
            u32 v = gfo_l[t][c];
            u32 icp = gic_l[t][c >> 1];
            float fg = bf2f((u16)v), og = bf2f((u16)(v >> 16));
            float ic = bf2f((u16)(icp >> ((c & 1) * 16)));
            cc = fg * cc + ic;
            float hn = og * tanhs(cc);
            *hp = f2h(hn);
            pr = fmaxf(pr, hn);
            hp += SLAB;
        }
        if (pool) pool[(size_t)sb * PLANE + (size_t)i * DD + c] = pr;
    }
}

// conv+LSTM update for one tail pixel from the LDS window
__device__ __forceinline__
float tail_px(const float (*wp)[130], const float* wls, const float* bls,
              int lr, int c, float& creg, float& pr) {
    float a0 = bls[0], a1 = bls[1], a2 = bls[2], a3 = bls[3];
    #pragma unroll
    for (int kh = 0; kh < 4; ++kh) {
        #pragma unroll
        for (int kw = 0; kw < 3; ++kw) {
            float v = wp[lr + kh][c + kw];
            a0 = fmaf(v, wls[kh*3+kw], a0);
            a1 = fmaf(v, wls[12+kh*3+kw], a1);
            a2 = fmaf(v, wls[24+kh*3+kw], a2);
            a3 = fmaf(v, wls[36+kh*3+kw], a3);
        }
    }
    float fg = sigm(a0), ig = sigm(a1), og = sigm(a2), cs = tanhs(a3);
    creg = fg * creg + ig * cs;
    float hn = og * tanhs(creg);
    pr = fmaxf(pr, hn);
    return hn;
}

// ---------------- tail rows 123..127: serial t, 5 rows, prefetched staging ----------------
__global__ __launch_bounds__(640)
void tail5_kernel(const u16* __restrict__ hsrc, u16* __restrict__ hdst,
                  float* __restrict__ pool,
                  const float* __restrict__ conv_w, const float* __restrict__ conv_b,
                  int layer) {
    const int sb = blockIdx.x;
    const int tid = threadIdx.x;
    const int slot = tid >> 7;         // 0..4 -> row 123+slot
    const int c = tid & 127;
    const int r = 123 + slot;
    __shared__ float win[2][12][130];  // data at [c+1]; col pads + lr 11 stay zero
    __shared__ float wls[48], bls[4];
    if (tid < 48) wls[tid] = conv_w[layer * 48 + tid];
    if (tid < 4)  bls[tid] = conv_b[layer * 4 + tid];
    for (int e = tid; e < 2 * 12 * 130; e += 640) ((float*)win)[e] = 0.f;

    const bool ldr = tid < 384;        // 6 rows x 64 col-pairs
    const int lrow = tid >> 6;         // 0..5
    const int lcp = tid & 63;
    const u16* gsrc = hsrc + (size_t)sb * PLANE + (size_t)(117 + lrow) * DD + 2 * lcp;
    u32 pre = 0;
    if (ldr) pre = *(const u32*)gsrc;  // t=0: slab 0 (zeroed)

    const int lr0 = 2 * slot;          // window start row for output r
    u16* hd = hdst ? hdst + SLAB + (size_t)sb * PLANE + (size_t)r * DD + c : nullptr;
    float creg = 0.f, pr = -1e30f;

    for (int t = 0; t < LL; ++t) {
        const int p = t & 1;
        __syncthreads();               // prior reads/writes of win[p] done
        if (ldr) {
            win[p][lrow][2 * lcp + 1] = h2f((u16)pre);
            win[p][lrow][2 * lcp + 2] = h2f((u16)(pre >> 16));
        }
        __syncthreads();
        if (ldr && t + 1 < LL)         // prefetch next step's rows (hides HBM latency)
            pre = *(const u32*)(gsrc + (size_t)(t + 1) * SLAB);
        float hn = tail_px(win[p], wls, bls, lr0, c, creg, pr);
        win[p ^ 1][6 + slot][c + 1] = hn;   // own h for t+1's window
        if (hd) { *hd = f2h(hn); hd += SLAB; }
    }
    if (pool) pool[(size_t)sb * PLANE + (size_t)r * DD + c] = pr;
}

// ---------------- final: linear + log_softmax ----------------
__global__ void final_kernel(const float* __restrict__ pool,
                             const float* __restrict__ lin_w,
                             const float* __restrict__ lin_b,
                             float* __restrict__ out) {
    const int b = blockIdx.x;
    const int tid = threadIdx.x;  // 256
    const int DD2 = DD * DD;
    const float* pq = pool + (size_t)b * DD2;
    const float* pa = pool + (size_t)(BB + b) * DD2;
    float s0 = 0.f, s1 = 0.f;
    for (int j = tid; j < DD2; j += 256) {
        float vq = pq[j], va = pa[j];
        s0 += vq * lin_w[j]           + va * lin_w[DD2 + j];
        s1 += vq * lin_w[2 * DD2 + j] + va * lin_w[3 * DD2 + j];
    }
    #pragma unroll
    for (int o = 32; o; o >>= 1) {
        s0 += __shfl_down(s0, o);
        s1 += __shfl_down(s1, o);
    }
    __shared__ float sh0[4], sh1[4];
    int wid = tid >> 6, lane = tid & 63;
    if (lane == 0) { sh0[wid] = s0; sh1[wid] = s1; }
    __syncthreads();
    if (tid == 0) {
        float a0 = sh0[0] + sh0[1] + sh0[2] + sh0[3] + lin_b[0];
        float a1 = sh1[0] + sh1[1] + sh1[2] + sh1[3] + lin_b[1];
        float m = fmaxf(a0, a1);
        float lse = m + logf(expf(a0 - m) + expf(a1 - m));
        out[b * 2 + 0] = a0 - lse;
        out[b * 2 + 1] = a1 - lse;
    }
}

extern "C" void kernel_launch(void* const* d_in, const int* in_sizes, int n_in,
                              void* d_out, int out_size, void* d_ws, size_t ws_size,
                              hipStream_t stream) {
    const int*   q      = (const int*)d_in[0];
    const int*   a      = (const int*)d_in[1];
    const float* embed  = (const float*)d_in[2];
    const float* conv_w = (const float*)d_in[3];
    const float* conv_b = (const float*)d_in[4];
    const float* lin_w  = (const float*)d_in[5];
    const float* lin_b  = (const float*)d_in[6];
    float* out = (float*)d_out;

    // ws: pool 4.2 | xe 1.31 | inv | pw 384B | h1 86 (41 f16 slabs) | h2 86  => ~178 MB
    float* ws      = (float*)d_ws;
    float* pool    = ws;
    float* xe_all  = pool + (size_t)NSB * PLANE;
    float* inv_all = xe_all + (size_t)NU * DD;
    u32*   pw      = (u32*)(inv_all + NU);
    u16*   h1      = (u16*)(pw + 96);
    u16*   h2      = h1 + (size_t)(LL + 1) * SLAB;

    // zero the t = -1 slabs
    hipMemsetAsync(h1, 0, SLAB * sizeof(u16), stream);
    hipMemsetAsync(h2, 0, SLAB * sizeof(u16), stream);

    prep_kernel<<<(NU + 3) / 4, 256, 0, stream>>>(q, a, embed, xe_all, inv_all);
    packw_kernel<<<1, 128, 0, stream>>>(conv_w, pw);

    // Levels [0,63) [63,95) [95,111) [111,119) [119,123); rows 123..127 serial tail.
    const int levr[5][2] = {{0,63},{63,32},{95,16},{111,8},{119,4}};

    for (int layer = 0; layer < 2; ++layer) {
        const u16* xt = layer ? h1 : nullptr;
        u16* hh       = layer ? h2 : h1;
        float* pl     = layer ? pool : nullptr;
        for (int k = 0; k < 5; ++k) {
            const int r0 = levr[k][0], nr = levr[k][1];
            if (layer == 0 && k == 0) {
                sep0_kernel<<<63 * NSB, 512, 0, stream>>>(
                    xe_all, inv_all, conv_w, conv_b, h1);
            } else {
                fused_level_kernel<<<nr * NSB, 512, 0, stream>>>(
                    xe_all, inv_all, xt, hh, pl, pw, conv_b, layer, r0, nr);
            }
        }
        tail5_kernel<<<NSB, 640, 0, stream>>>(hh, layer ? nullptr : h1,
                                              pl, conv_w, conv_b, layer);
    }

    final_kernel<<<BB, 256, 0, stream>>>(pool, lin_w, lin_b, out);
}

// Round 21
// 403.592 us; speedup vs baseline: 1.2468x; 1.1174x over previous
//
#include <hip/hip_runtime.h>
#include <math.h>

#define BB 32
#define LL 40
#define DD 128
#define NSB 64                        // 2 seq * 32 batch
#define NU  (NSB * LL)                // 2560
#define PLANE (DD * DD)               // 16384
#define SLAB ((size_t)NSB * PLANE)    // u16 elements per t-slab (2 MB)

typedef unsigned short u16;
typedef unsigned int u32;
typedef _Float16 h2t __attribute__((ext_vector_type(2)));
typedef __fp16  p2t __attribute__((ext_vector_type(2)));   // cvt_pkrtz return type

// ---- 16-bit helpers: h state is fp16 (|h|<1 -> fp16 beats bf16 there) ----
__device__ __forceinline__ u16 f2h(float f) {
    union { _Float16 h; u16 u; } v; v.h = (_Float16)f; return v.u;
}
__device__ __forceinline__ float h2f(u16 b) {
    union { u16 u; _Float16 h; } v; v.u = b; return (float)v.h;
}
__device__ __forceinline__ h2t b2h(u32 b) {
    union { u32 u; h2t h; } v; v.u = b; return v.h;
}
__device__ __forceinline__ u32 pk16(float x, float y) {   // v_cvt_pkrtz_f16_f32
    union { p2t h; u32 u; } v; v.h = __builtin_amdgcn_cvt_pkrtz(x, y); return v.u;
}
// packed f16 dot2 with f32 accumulate: D = a.x*b.x + a.y*b.y + c
__device__ __forceinline__ float fdot2(u32 a, u32 b, float c) {
    return __builtin_amdgcn_fdot2(b2h(a), b2h(b), c, false);
}

// bf16 (gate LDS scratch only)
__device__ __forceinline__ u16 f2bf(float f) {
    union { float f; unsigned u; } v; v.f = f;
    unsigned u = v.u;
    u += 0x7fff + ((u >> 16) & 1);    // RNE
    return (u16)(u >> 16);
}
__device__ __forceinline__ float bf2f(u16 b) {
    union { unsigned u; float f; } v; v.u = ((unsigned)b) << 16;
    return v.f;
}
// Fast math: v_rcp_f32 instead of the IEEE div sequence.
__device__ __forceinline__ float rcpf(float x) { return __builtin_amdgcn_rcpf(x); }
__device__ __forceinline__ float sigm(float x)  { return rcpf(1.f + __expf(-x)); }
__device__ __forceinline__ float tanhs(float x) { return fmaf(2.f, rcpf(1.f + __expf(-2.f * x)), -1.f); }

// ---------------- prep: xe rows + inverse squared norms ----------------
__global__ void prep_kernel(const int* __restrict__ q, const int* __restrict__ a,
                            const float* __restrict__ embed,
                            float* __restrict__ xe_all, float* __restrict__ inv_all) {
    int u = blockIdx.x * 4 + (threadIdx.x >> 6);
    int lane = threadIdx.x & 63;
    if (u >= NU) return;
    int sb = u / LL, t = u % LL;
    int s = sb >> 5, b = sb & 31;
    const int* idx = s ? a : q;
    int e = idx[b * LL + t];
    const float* row = embed + (size_t)e * DD;
    float v0 = row[lane], v1 = row[lane + 64];
    xe_all[(size_t)u * DD + lane] = v0;
    xe_all[(size_t)u * DD + lane + 64] = v1;
    float d = v0 * v0 + v1 * v1;
    #pragma unroll
    for (int o = 32; o; o >>= 1) d += __shfl_down(d, o);
    if (lane == 0) inv_all[u] = 1.f / (d + 1e-4f);
}

// ---------------- pack conv weights into f16 dot2 pairs ----------------
// pw[l*48 + kh*12 + g*3 + s]: s=0 -> (w0,w1); s=1 -> (w2,0); s=2 -> (0,w2)
__global__ void packw_kernel(const float* __restrict__ conv_w, u32* __restrict__ pw) {
    int id = threadIdx.x;
    if (id >= 96) return;
    int l = id / 48, r = id - l * 48;
    int kh = r / 12, g = (r - kh * 12) / 3, s = r % 3;
    const float* w = conv_w + l * 48 + g * 12 + kh * 3;
    float x, y;
    if (s == 0)      { x = w[0]; y = w[1]; }
    else if (s == 1) { x = w[2]; y = 0.f; }
    else             { x = 0.f;  y = w[2]; }
    pw[id] = (u32)f2h(x) | ((u32)f2h(y) << 16);   // RNE per element
}

// ---------------- layer1 rows 0..62: separable density gates + in-block scan ----------------
// 1-D swizzled grid (63*NSB) x 512. Block: one output row i of one sb, all 40 t.
// NOTE: conv weights live in LDS (wls) because the U-computation indexes them at
// RUNTIME — a per-thread w[48] array would spill to scratch (396 MB of traffic).
__global__ __launch_bounds__(512)
void sep0_kernel(const float* __restrict__ xe_all, const float* __restrict__ inv_all,
                 const float* __restrict__ conv_w, const float* __restrict__ conv_b,
                 u16* __restrict__ h1) {
    const int nchunk = (63 * NSB) / 8;
    const int logical = ((int)blockIdx.x % 8) * nchunk + (int)blockIdx.x / 8;
    const int i  = logical % 63;
    const int sb = logical / 63;
    const int tid = threadIdx.x;
    const int cp = tid & 63;
    const int t0 = tid >> 6;          // 0..7, wave-uniform
    const int c0 = 2 * cp;

    __shared__ float xe_s[LL][DD];    // 20.5 KB
    __shared__ float U[LL][12];
    __shared__ u32 gfo_l[LL][DD];     // bf16-packed internal gate scratch
    __shared__ u32 gic_l[LL][DD / 2];
    __shared__ float wls[48];

    if (tid < 48) wls[tid] = conv_w[tid];
    float b4[4];
    #pragma unroll
    for (int k = 0; k < 4; ++k) b4[k] = conv_b[k];

    const float2* xsrc = (const float2*)(xe_all + (size_t)(sb * LL) * DD);
    for (int e = tid; e < LL * DD / 2; e += 512)
        ((float2*)xe_s)[e] = xsrc[e];
    __syncthreads();

    if (tid < LL * 12) {
        int t = tid / 12, k = tid - t * 12;
        int g = k / 3, kw = k - g * 3;
        int base = 2 * i - 1;
        float s = 0.f;
        #pragma unroll
        for (int kh = 0; kh < 4; ++kh) {
            int r = base + kh;
            if (r >= 0) s = fmaf(wls[g * 12 + kh * 3 + kw], xe_s[t][r], s);
        }
        U[t][k] = s * inv_all[sb * LL + t];
    }
    __syncthreads();

    #pragma unroll
    for (int k5 = 0; k5 < 5; ++k5) {
        const int t = t0 + 8 * k5;
        float4 u0 = *(const float4*)&U[t][0];
        float4 u1 = *(const float4*)&U[t][4];
        float4 u2 = *(const float4*)&U[t][8];
        float xl = cp > 0 ? xe_s[t][c0 - 1] : 0.f;
        float xm = xe_s[t][c0];
        float xr = xe_s[t][c0 + 1];
        float x2 = cp < 63 ? xe_s[t][c0 + 2] : 0.f;
        float a0 = fmaf(u0.x, xl, fmaf(u0.y, xm, fmaf(u0.z, xr, b4[0])));
        float a1 = fmaf(u0.w, xl, fmaf(u1.x, xm, fmaf(u1.y, xr, b4[1])));
        float a2 = fmaf(u1.z, xl, fmaf(u1.w, xm, fmaf(u2.x, xr, b4[2])));
        float a3 = fmaf(u2.y, xl, fmaf(u2.z, xm, fmaf(u2.w, xr, b4[3])));
        float d0 = fmaf(u0.x, xm, fmaf(u0.y, xr, fmaf(u0.z, x2, b4[0])));
        float d1 = fmaf(u0.w, xm, fmaf(u1.x, xr, fmaf(u1.y, x2, b4[1])));
        float d2 = fmaf(u1.z, xm, fmaf(u1.w, xr, fmaf(u2.x, x2, b4[2])));
        float d3 = fmaf(u2.y, xm, fmaf(u2.z, xr, fmaf(u2.w, x2, b4[3])));
        float fg0 = sigm(a0), ic0 = sigm(a1) * tanhs(a3), og0 = sigm(a2);
        float fg1 = sigm(d0), ic1 = sigm(d1) * tanhs(d3), og1 = sigm(d2);
        u32 f0 = (u32)f2bf(fg0) | ((u32)f2bf(og0) << 16);
        u32 f1 = (u32)f2bf(fg1) | ((u32)f2bf(og1) << 16);
        *(uint2*)&gfo_l[t][c0] = make_uint2(f0, f1);
        gic_l[t][cp] = (u32)f2bf(ic0) | ((u32)f2bf(ic1) << 16);
    }
    __syncthreads();

    if (tid < DD) {                   // in-block scan; h stored f16
        const int c = tid;
        u16* hp = h1 + SLAB + (size_t)sb * PLANE + (size_t)i * DD + c;
        float cc = 0.f;
        #pragma unroll 4
        for (int t = 0; t < LL; ++t) {
            u32 v = gfo_l[t][c];
            u32 icp = gic_l[t][c >> 1];
            float fg = bf2f((u16)v), og = bf2f((u16)(v >> 16));
            float ic = bf2f((u16)(icp >> ((c & 1) * 16)));
            cc = fg * cc + ic;
            *hp = f2h(og * tanhs(cc));
            hp += SLAB;
        }
    }
}

// ---------------- fused level: dot2-f16 gates (t-parallel, LDS scratch) + scan ----------------
// 1-D swizzled grid (nr*NSB) x 512. Block: output row i = r0 + (logical % nr), sb = logical / nr.
// Conv: per gate/kh/px-pair = 4 chained v_dot2_f32_f16 with SGPR-resident packed weights.
// Window loads double-buffered across the 5 t-iterations (hide L3 latency under compute).
__global__ __launch_bounds__(512, 8)
void fused_level_kernel(const float* __restrict__ xe_all, const float* __restrict__ inv_all,
                        const u16* __restrict__ xt_h1,   // layer1: h1; layer0: null (density)
                        u16* __restrict__ h_own,
                        float* __restrict__ pool,        // layer1 only
                        const u32* __restrict__ pw,      // packed f16 weight pairs
                        const float* __restrict__ conv_b,
                        int layer, int r0, int nr) {
    const int nchunk = (nr * NSB) / 8;
    const int logical = ((int)blockIdx.x % 8) * nchunk + (int)blockIdx.x / 8;
    const int i  = r0 + logical % nr;
    const int sb = logical / nr;
    const int tid = threadIdx.x;
    const int cp = tid & 63;
    const int t0 = tid >> 6;          // 0..7 (wave-uniform)
    const int c0 = 2 * cp;

    __shared__ u32 gfo_l[LL][DD];     // fg | og<<16, per px      (20.5 KB)
    __shared__ u32 gic_l[LL][DD / 2]; // ic px-pairs              (10.25 KB)

    u32 uwp[48];                      // uniform, literal-indexed -> SGPRs
    #pragma unroll
    for (int k = 0; k < 48; ++k) uwp[k] = pw[layer * 48 + k];
    float b4[4];
    #pragma unroll
    for (int k = 0; k < 4; ++k) b4[k] = conv_b[layer * 4 + k];

    const u16* sp[4];
    bool dens[4];
    int wrow[4];
    #pragma unroll
    for (int kh = 0; kh < 4; ++kh) {
        const int wr = 2 * i - 1 + kh;
        wrow[kh] = wr;
        dens[kh] = false;
        sp[kh] = nullptr;
        if (wr >= 0 && wr < 2 * DD) {
            if (wr < DD) {
                if (layer == 0) dens[kh] = true;
                else sp[kh] = xt_h1 + (size_t)(t0 + 1) * SLAB + (size_t)sb * PLANE + (size_t)wr * DD;
            } else {
                sp[kh] = h_own + (size_t)t0 * SLAB + (size_t)sb * PLANE + (size_t)(wr - DD) * DD;
            }
        }
    }
    const bool cL = (cp > 0), cR = (cp < 63);
    const u32 maskA = cL ? 0xFFFFFFFFu : 0xFFFF0000u;   // zero vA at left edge
    const u32 maskC = cR ? 0xFFFFFFFFu : 0x0000FFFFu;   // zero vC at right edge
    const bool anyd = (layer == 0) && (2 * i - 1 < DD);
    const float* xe_u = xe_all + ((size_t)sb * LL + t0) * DD;
    const float* ip   = inv_all + sb * LL + t0;

    // software pipeline: prefetch iteration k+1's 4 window-row words during iteration k
    u32 nxt[4];
    #pragma unroll
    for (int kh = 0; kh < 4; ++kh) {
        nxt[kh] = 0;
        if (sp[kh]) { nxt[kh] = *(const u32*)(sp[kh] + c0); sp[kh] += 8 * SLAB; }
    }

    #pragma unroll
    for (int k = 0; k < 5; ++k) {
        const int t = t0 + 8 * k;
        u32 cur[4];
        #pragma unroll
        for (int kh = 0; kh < 4; ++kh) {
            cur[kh] = nxt[kh];
            if (k < 4 && sp[kh]) { nxt[kh] = *(const u32*)(sp[kh] + c0); sp[kh] += 8 * SLAB; }
        }
        float a0 = b4[0], a1 = b4[1], a2 = b4[2], a3 = b4[3];   // px0
        float d0 = b4[0], d1 = b4[1], d2 = b4[2], d3 = b4[3];   // px1
        float x_1 = 0.f, xA = 0.f, xB = 0.f, x2 = 0.f, invv = 0.f;
        if (anyd) {
            invv = *ip;
            x_1 = cL ? xe_u[c0 - 1] : 0.f;
            xA = xe_u[c0]; xB = xe_u[c0 + 1];
            x2 = cR ? xe_u[c0 + 2] : 0.f;
        }
        #pragma unroll
        for (int kh = 0; kh < 4; ++kh) {
            u32 pA, pB, pC;           // packed f16: (vA,vB0), (vB0,vB1), (vB1,vC)
            if (dens[kh]) {
                float p = invv * xe_u[wrow[kh]];
                pA = pk16(p * x_1, p * xA);
                pB = pk16(p * xA, p * xB);
                pC = pk16(p * xB, p * x2);
            } else {
                u32 pb = cur[kh];
                u32 up = __shfl_up(pb, 1);
                u32 dn = __shfl_down(pb, 1);
                pA = __builtin_amdgcn_alignbit(pb, up, 16) & maskA;
                pB = pb;
                pC = __builtin_amdgcn_alignbit(dn, pb, 16) & maskC;
            }
            const int wbase = kh * 12;
            // px0: vA*w0 + vB0*w1 + vB1*w2 ; px1: vB0*w0 + vB1*w1 + vC*w2
            a0 = fdot2(pA, uwp[wbase + 0], a0);  a0 = fdot2(pC, uwp[wbase + 1], a0);
            d0 = fdot2(pB, uwp[wbase + 0], d0);  d0 = fdot2(pC, uwp[wbase + 2], d0);
            a1 = fdot2(pA, uwp[wbase + 3], a1);  a1 = fdot2(pC, uwp[wbase + 4], a1);
            d1 = fdot2(pB, uwp[wbase + 3], d1);  d1 = fdot2(pC, uwp[wbase + 5], d1);
            a2 = fdot2(pA, uwp[wbase + 6], a2);  a2 = fdot2(pC, uwp[wbase + 7], a2);
            d2 = fdot2(pB, uwp[wbase + 6], d2);  d2 = fdot2(pC, uwp[wbase + 8], d2);
            a3 = fdot2(pA, uwp[wbase + 9], a3);  a3 = fdot2(pC, uwp[wbase + 10], a3);
            d3 = fdot2(pB, uwp[wbase + 9], d3);  d3 = fdot2(pC, uwp[wbase + 11], d3);
        }
        float fg0 = sigm(a0), ic0 = sigm(a1) * tanhs(a3), og0 = sigm(a2);
        float fg1 = sigm(d0), ic1 = sigm(d1) * tanhs(d3), og1 = sigm(d2);
        u32 f0 = (u32)f2bf(fg0) | ((u32)f2bf(og0) << 16);
        u32 f1 = (u32)f2bf(fg1) | ((u32)f2bf(og1) << 16);
        *(uint2*)&gfo_l[t][c0] = make_uint2(f0, f1);
        gic_l[t][cp] = (u32)f2bf(ic0) | ((u32)f2bf(ic1) << 16);
        if (anyd) { xe_u += 8 * DD; ip += 8; }
    }
    __syncthreads();

    if (tid < DD) {                    // phase 2: per-pixel scan from LDS; h stored f16
        const int c = tid;
        u16* hp = h_own + SLAB + (size_t)sb * PLANE + (size_t)i * DD + c;
        float cc = 0.f, pr = -1e30f;
        #pragma unroll 4
        for (int t = 0; t < LL; ++t) {
            u32 v = gfo_l[t][c];
            u32 icp = gic_l[t][c >> 1];
            float fg = bf2f((u16)v), og = bf2f((u16)(v >> 16));
            float ic = bf2f((u16)(icp >> ((c & 1) * 16)));
            cc = fg * cc + ic;
            float hn = og * tanhs(cc);
            *hp = f2h(hn);
            pr = fmaxf(pr, hn);
            hp += SLAB;
        }
        if (pool) pool[(size_t)sb * PLANE + (size_t)i * DD + c] = pr;
    }
}

// conv+LSTM update for one tail pixel from the LDS window
__device__ __forceinline__
float tail_px(const float (*wp)[130], const float* wls, const float* bls,
              int lr, int c, float& creg, float& pr) {
    float a0 = bls[0], a1 = bls[1], a2 = bls[2], a3 = bls[3];
    #pragma unroll
    for (int kh = 0; kh < 4; ++kh) {
        #pragma unroll
        for (int kw = 0; kw < 3; ++kw) {
            float v = wp[lr + kh][c + kw];
            a0 = fmaf(v, wls[kh*3+kw], a0);
            a1 = fmaf(v, wls[12+kh*3+kw], a1);
            a2 = fmaf(v, wls[24+kh*3+kw], a2);
            a3 = fmaf(v, wls[36+kh*3+kw], a3);
        }
    }
    float fg = sigm(a0), ig = sigm(a1), og = sigm(a2), cs = tanhs(a3);
    creg = fg * creg + ig * cs;
    float hn = og * tanhs(creg);
    pr = fmaxf(pr, hn);
    return hn;
}

// ---------------- tail rows 123..127: serial t, 5 rows, prefetched staging ----------------
__global__ __launch_bounds__(640)
void tail5_kernel(const u16* __restrict__ hsrc, u16* __restrict__ hdst,
                  float* __restrict__ pool,
                  const float* __restrict__ conv_w, const float* __restrict__ conv_b,
                  int layer) {
    const int sb = blockIdx.x;
    const int tid = threadIdx.x;
    const int slot = tid >> 7;         // 0..4 -> row 123+slot
    const int c = tid & 127;
    const int r = 123 + slot;
    __shared__ float win[2][12][130];  // data at [c+1]; col pads + lr 11 stay zero
    __shared__ float wls[48], bls[4];
    if (tid < 48) wls[tid] = conv_w[layer * 48 + tid];
    if (tid < 4)  bls[tid] = conv_b[layer * 4 + tid];
    for (int e = tid; e < 2 * 12 * 130; e += 640) ((float*)win)[e] = 0.f;

    const bool ldr = tid < 384;        // 6 rows x 64 col-pairs
    const int lrow = tid >> 6;         // 0..5
    const int lcp = tid & 63;
    const u16* gsrc = hsrc + (size_t)sb * PLANE + (size_t)(117 + lrow) * DD + 2 * lcp;
    u32 pre = 0;
    if (ldr) pre = *(const u32*)gsrc;  // t=0: slab 0 (zeroed)

    const int lr0 = 2 * slot;          // window start row for output r
    u16* hd = hdst ? hdst + SLAB + (size_t)sb * PLANE + (size_t)r * DD + c : nullptr;
    float creg = 0.f, pr = -1e30f;

    for (int t = 0; t < LL; ++t) {
        const int p = t & 1;
        __syncthreads();               // prior reads/writes of win[p] done
        if (ldr) {
            win[p][lrow][2 * lcp + 1] = h2f((u16)pre);
            win[p][lrow][2 * lcp + 2] = h2f((u16)(pre >> 16));
        }
        __syncthreads();
        if (ldr && t + 1 < LL)         // prefetch next step's rows (hides HBM latency)
            pre = *(const u32*)(gsrc + (size_t)(t + 1) * SLAB);
        float hn = tail_px(win[p], wls, bls, lr0, c, creg, pr);
        win[p ^ 1][6 + slot][c + 1] = hn;   // own h for t+1's window
        if (hd) { *hd = f2h(hn); hd += SLAB; }
    }
    if (pool) pool[(size_t)sb * PLANE + (size_t)r * DD + c] = pr;
}

// ---------------- final: linear + log_softmax ----------------
__global__ void final_kernel(const float* __restrict__ pool,
                             const float* __restrict__ lin_w,
                             const float* __restrict__ lin_b,
                             float* __restrict__ out) {
    const int b = blockIdx.x;
    const int tid = threadIdx.x;  // 256
    const int DD2 = DD * DD;
    const float* pq = pool + (size_t)b * DD2;
    const float* pa = pool + (size_t)(BB + b) * DD2;
    float s0 = 0.f, s1 = 0.f;
    for (int j = tid; j < DD2; j += 256) {
        float vq = pq[j], va = pa[j];
        s0 += vq * lin_w[j]           + va * lin_w[DD2 + j];
        s1 += vq * lin_w[2 * DD2 + j] + va * lin_w[3 * DD2 + j];
    }
    #pragma unroll
    for (int o = 32; o; o >>= 1) {
        s0 += __shfl_down(s0, o);
        s1 += __shfl_down(s1, o);
    }
    __shared__ float sh0[4], sh1[4];
    int wid = tid >> 6, lane = tid & 63;
    if (lane == 0) { sh0[wid] = s0; sh1[wid] = s1; }
    __syncthreads();
    if (tid == 0) {
        float a0 = sh0[0] + sh0[1] + sh0[2] + sh0[3] + lin_b[0];
        float a1 = sh1[0] + sh1[1] + sh1[2] + sh1[3] + lin_b[1];
        float m = fmaxf(a0, a1);
        float lse = m + logf(expf(a0 - m) + expf(a1 - m));
        out[b * 2 + 0] = a0 - lse;
        out[b * 2 + 1] = a1 - lse;
    }
}

extern "C" void kernel_launch(void* const* d_in, const int* in_sizes, int n_in,
                              void* d_out, int out_size, void* d_ws, size_t ws_size,
                              hipStream_t stream) {
    const int*   q      = (const int*)d_in[0];
    const int*   a      = (const int*)d_in[1];
    const float* embed  = (const float*)d_in[2];
    const float* conv_w = (const float*)d_in[3];
    const float* conv_b = (const float*)d_in[4];
    const float* lin_w  = (const float*)d_in[5];
    const float* lin_b  = (const float*)d_in[6];
    float* out = (float*)d_out;

    // ws: pool 4.2 | xe 1.31 | inv | pw 384B | h1 86 (41 f16 slabs) | h2 86  => ~178 MB
    float* ws      = (float*)d_ws;
    float* pool    = ws;
    float* xe_all  = pool + (size_t)NSB * PLANE;
    float* inv_all = xe_all + (size_t)NU * DD;
    u32*   pw      = (u32*)(inv_all + NU);
    u16*   h1      = (u16*)(pw + 96);
    u16*   h2      = h1 + (size_t)(LL + 1) * SLAB;

    // zero the t = -1 slabs
    hipMemsetAsync(h1, 0, SLAB * sizeof(u16), stream);
    hipMemsetAsync(h2, 0, SLAB * sizeof(u16), stream);

    prep_kernel<<<(NU + 3) / 4, 256, 0, stream>>>(q, a, embed, xe_all, inv_all);
    packw_kernel<<<1, 128, 0, stream>>>(conv_w, pw);

    // Levels [0,63) [63,95) [95,111) [111,119) [119,123); rows 123..127 serial tail.
    const int levr[5][2] = {{0,63},{63,32},{95,16},{111,8},{119,4}};

    for (int layer = 0; layer < 2; ++layer) {
        const u16* xt = layer ? h1 : nullptr;
        u16* hh       = layer ? h2 : h1;
        float* pl     = layer ? pool : nullptr;
        for (int k = 0; k < 5; ++k) {
            const int r0 = levr[k][0], nr = levr[k][1];
            if (layer == 0 && k == 0) {
                sep0_kernel<<<63 * NSB, 512, 0, stream>>>(
                    xe_all, inv_all, conv_w, conv_b, h1);
            } else {
                fused_level_kernel<<<nr * NSB, 512, 0, stream>>>(
                    xe_all, inv_all, xt, hh, pl, pw, conv_b, layer, r0, nr);
            }
        }
        tail5_kernel<<<NSB, 640, 0, stream>>>(hh, layer ? nullptr : h1,
                                              pl, conv_w, conv_b, layer);
    }

    final_kernel<<<BB, 256, 0, stream>>>(pool, lin_w, lin_b, out);
}